// Round 3
// baseline (335.263 us; speedup 1.0000x reference)
//
#include <hip/hip_runtime.h>
#include <hip/hip_bf16.h>
#include <math.h>

typedef unsigned short u16;
typedef unsigned int u32;
typedef __attribute__((ext_vector_type(8))) short short8;   // 8 bf16 = 4 VGPRs
typedef __attribute__((ext_vector_type(4))) float float4_;  // 4 fp32 acc

#define S_LEN 1024
#define C_DIM 640
#define HEADS 10
#define HDIM 64
#define M_TOT 4096                  // B*S
#define WSZ (C_DIM * C_DIM)         // 409600
#define TX ((size_t)M_TOT * C_DIM)  // 2,621,440
#define SHIFT_C 0.6931471805599453f

static __device__ __forceinline__ float bf2f(u16 u) {
    unsigned int x = ((unsigned int)u) << 16;
    float f; __builtin_memcpy(&f, &x, 4); return f;
}
static __device__ __forceinline__ u16 f2bf(float f) {
    unsigned int x; __builtin_memcpy(&x, &f, 4);
    x = x + 0x7fffu + ((x >> 16) & 1u);   // RNE
    return (u16)(x >> 16);
}

// ---------------------------------------------------------------------------
// Input-dtype probe: read first 64 dwords of X; count 16-bit halves whose
// bf16 exponent field is "sane" (2^-27..2^23). True bf16 N(0,1) data: ~128/128
// sane. f32 data: high halves sane, low halves are uniform mantissa bits
// (~20% sane) -> total ~77/128. Threshold 110.
// ---------------------------------------------------------------------------
static __device__ int detect_bf16(const void* X) {
    const u32* p = (const u32*)X;
    int sane = 0;
    for (int i = 0; i < 64; i++) {
        u32 w = p[i];
        int ea = (int)((w >> 7)  & 0xFF);
        int eb = (int)((w >> 23) & 0xFF);
        sane += (ea >= 100 && ea <= 150);
        sane += (eb >= 100 && eb <= 150);
    }
    return sane >= 110;
}

// ---------------------------------------------------------------------------
// Convert inputs: X,W0..W3 -> bf16 (Xb, Wb contiguous); biases -> f32 Bf.
// Handles both f32-world (convert) and bf16-world (copy) per the probe.
// Writes the flag (1 = bf16 inputs) for the final GEMM's store dtype.
// ---------------------------------------------------------------------------
__global__ __launch_bounds__(256) void convert_inputs(
    const void* X, const void* W0, const void* W1, const void* W2, const void* W3,
    const void* B0, const void* B1, const void* B2, const void* B3,
    u16* __restrict__ Xb, u16* __restrict__ Wb, float* __restrict__ Bf,
    int* __restrict__ flag)
{
    __shared__ int is_bf;
    if (threadIdx.x == 0) {
        int f = detect_bf16(X);
        is_bf = f;
        if (blockIdx.x == 0) *flag = f;   // all blocks agree; single write
    }
    __syncthreads();
    const int f = is_bf;

    const size_t WREG = TX + 4 * (size_t)WSZ;
    const size_t TOT  = WREG + 4 * C_DIM;
    size_t idx4 = ((size_t)blockIdx.x * 256 + threadIdx.x) * 4;
    if (idx4 >= TOT) return;

    const void* src; size_t off; int kind;  // kind 0: ->bf16, 1: bias ->f32
    u16* dst16 = nullptr; float* dstf = nullptr;
    if (idx4 < TX) {
        src = X; off = idx4; dst16 = Xb + off; kind = 0;
    } else if (idx4 < WREG) {
        size_t r = idx4 - TX; int w = (int)(r / WSZ); off = r % WSZ;
        src = (w == 0) ? W0 : ((w == 1) ? W1 : ((w == 2) ? W2 : W3));
        dst16 = Wb + (size_t)w * WSZ + off; kind = 0;
    } else {
        size_t r = idx4 - WREG; int w = (int)(r / C_DIM); off = r % C_DIM;
        src = (w == 0) ? B0 : ((w == 1) ? B1 : ((w == 2) ? B2 : B3));
        dstf = Bf + (size_t)w * C_DIM + off; kind = 1;
    }

    if (!f) {   // f32 inputs
        float4 v = *(const float4*)((const float*)src + off);
        if (kind == 0) {
            union { u16 s[4]; uint2 u; } pk;
            pk.s[0] = f2bf(v.x); pk.s[1] = f2bf(v.y);
            pk.s[2] = f2bf(v.z); pk.s[3] = f2bf(v.w);
            *(uint2*)dst16 = pk.u;
        } else {
            *(float4*)dstf = v;
        }
    } else {    // bf16 inputs
        union { uint2 u; u16 s[4]; } pk;
        pk.u = *(const uint2*)((const u16*)src + off);
        if (kind == 0) {
            *(uint2*)dst16 = pk.u;
        } else {
            dstf[0] = bf2f(pk.s[0]); dstf[1] = bf2f(pk.s[1]);
            dstf[2] = bf2f(pk.s[2]); dstf[3] = bf2f(pk.s[3]);
        }
    }
}

// ---------------------------------------------------------------------------
// GEMM: Out = A @ W^T + bias. A [4096,640] bf16, Wbase + z*WSZ = W_z [640,640]
// bf16 row-major (B[k][n] = W[n][k]), Bf + z*640 = f32 bias. 128x128 tile,
// BK=32, 4 waves, 4x4 16x16x32 MFMA frags/wave. LDS ld 40 (2-way conflicts
// only). Non-final (Of==null): bf16 store to O{z}. Final: f32 to Of unless
// *flag (bf16 world) -> bf16 to O0.
// ---------------------------------------------------------------------------
__global__ __launch_bounds__(256) void gemm_bt(
    const u16* __restrict__ A, const u16* __restrict__ Wbase,
    const float* __restrict__ Bf,
    u16* O0, u16* O1, u16* O2,
    float* Of, const int* __restrict__ flag)
{
    const int z = blockIdx.z;
    const u16* W    = Wbase + (size_t)z * WSZ;
    const float* bias = Bf + (size_t)z * C_DIM;
    u16* Out = (z == 0) ? O0 : ((z == 1) ? O1 : O2);
    const bool wf32 = (Of != nullptr) && (*flag == 0);

    __shared__ u16 Al[128 * 40];
    __shared__ u16 Wl[128 * 40];

    const int tid  = threadIdx.x;
    const int wave = tid >> 6;
    const int lane = tid & 63;
    const int l16  = lane & 15;
    const int quad = lane >> 4;
    const int m0 = blockIdx.x * 128;
    const int n0 = blockIdx.y * 128;
    const int wm = (wave & 1) * 64;
    const int wn = (wave >> 1) * 64;

    const int srow = tid >> 2;          // 0..63 (two passes -> 128 rows)
    const int scol = (tid & 3) * 8;     // k-offset in elements

    float4_ acc[4][4] = {};

    for (int k0 = 0; k0 < C_DIM; k0 += 32) {
        #pragma unroll
        for (int i = 0; i < 2; i++) {
            int row = srow + i * 64;
            uint4 va = *(const uint4*)(A + (size_t)(m0 + row) * C_DIM + k0 + scol);
            uint4 vw = *(const uint4*)(W + (size_t)(n0 + row) * C_DIM + k0 + scol);
            *(uint4*)(&Al[row * 40 + scol]) = va;
            *(uint4*)(&Wl[row * 40 + scol]) = vw;
        }
        __syncthreads();

        short8 af[4], bfr[4];
        #pragma unroll
        for (int t = 0; t < 4; t++) {
            af[t]  = *(const short8*)(&Al[(wm + t * 16 + l16) * 40 + quad * 8]);
            bfr[t] = *(const short8*)(&Wl[(wn + t * 16 + l16) * 40 + quad * 8]);
        }
        #pragma unroll
        for (int mt = 0; mt < 4; mt++)
            #pragma unroll
            for (int nt = 0; nt < 4; nt++)
                acc[mt][nt] = __builtin_amdgcn_mfma_f32_16x16x32_bf16(
                    af[mt], bfr[nt], acc[mt][nt], 0, 0, 0);
        __syncthreads();
    }

    #pragma unroll
    for (int mt = 0; mt < 4; mt++) {
        #pragma unroll
        for (int nt = 0; nt < 4; nt++) {
            int col = n0 + wn + nt * 16 + l16;
            float bv = bias[col];
            #pragma unroll
            for (int r = 0; r < 4; r++) {
                int row = m0 + wm + mt * 16 + quad * 4 + r;
                float val = acc[mt][nt][r] + bv;
                size_t idx = (size_t)row * C_DIM + col;
                if (wf32) Of[idx] = val;
                else      Out[idx] = f2bf(val);
            }
        }
    }
}

// ---------------------------------------------------------------------------
// AdaIN stats: per (tensor t in {q,k}, b, h, d): mean/std over S (ddof=1).
// ---------------------------------------------------------------------------
__global__ __launch_bounds__(256) void adain_stats(
    const u16* __restrict__ Qp, const u16* __restrict__ Kp,
    float* __restrict__ meanArr, float* __restrict__ stdArr)
{
    const int bid = blockIdx.x;          // t*40 + b*10 + h
    const int t = bid / 40;
    const int rem = bid % 40;
    const int b = rem / 10;
    const int h = rem % 10;
    const u16* X = t ? Kp : Qp;

    const int tid = threadIdx.x;
    const int d  = tid & 63;
    const int sg = tid >> 6;

    float sum = 0.f, sq = 0.f;
    for (int s = sg; s < S_LEN; s += 4) {
        float v = bf2f(X[(size_t)(b * S_LEN + s) * C_DIM + h * HDIM + d]);
        sum += v; sq += v * v;
    }
    __shared__ float ssum[4][64], ssq[4][64];
    ssum[sg][d] = sum; ssq[sg][d] = sq;
    __syncthreads();
    if (tid < 64) {
        float Sv = 0.f, Qv = 0.f;
        #pragma unroll
        for (int g = 0; g < 4; g++) { Sv += ssum[g][tid]; Qv += ssq[g][tid]; }
        float mean = Sv * (1.f / 1024.f);
        float var  = (Qv - Sv * Sv * (1.f / 1024.f)) * (1.f / 1023.f);
        int idx = ((t * 4 + b) * HEADS + h) * HDIM + tid;
        meanArr[idx] = mean;
        stdArr[idx]  = sqrtf(fmaxf(var, 0.f) + 1e-5f);
    }
}

// ---------------------------------------------------------------------------
// AdaIN apply: restyle batches 1 and 3 in-place (ref = batch-1). 0,2 identity.
// ---------------------------------------------------------------------------
__global__ __launch_bounds__(256) void adain_apply(
    u16* __restrict__ Qp, u16* __restrict__ Kp,
    const float* __restrict__ meanArr, const float* __restrict__ stdArr)
{
    const int idx = blockIdx.x * 256 + threadIdx.x;   // 2*2*1024*640 exact
    const int t  = idx / (2 * S_LEN * C_DIM);
    const int r  = idx % (2 * S_LEN * C_DIM);
    const int bi = r / (S_LEN * C_DIM);               // 0,1 -> b=1,3
    const int r2 = r % (S_LEN * C_DIM);
    const int s  = r2 / C_DIM;
    const int c  = r2 % C_DIM;
    const int b  = bi * 2 + 1;
    const int h  = c / HDIM, d = c % HDIM;

    u16* X = t ? Kp : Qp;
    const int si   = ((t * 4 + b) * HEADS + h) * HDIM + d;
    const int sref = ((t * 4 + (b - 1)) * HEADS + h) * HDIM + d;
    float scale = stdArr[sref] / stdArr[si];
    float off   = meanArr[sref] - meanArr[si] * scale;
    size_t g = (size_t)(b * S_LEN + s) * C_DIM + c;
    X[g] = f2bf(bf2f(X[g]) * scale + off);
}

// ---------------------------------------------------------------------------
// Flash attention with shared-KV concat. Block = (b, h, 64-row Q-tile); 4
// waves x 16 Q-rows. kv = 2048 in tiles of 64: first 1024 own batch, second
// 1024 ref batch (b & 2) with +log(2) shift. All buffers distinct (no alias).
// ---------------------------------------------------------------------------
__global__ __launch_bounds__(256) void attn_kernel(
    const u16* __restrict__ Q, const u16* __restrict__ K, const u16* __restrict__ V,
    u16* __restrict__ Oattn)
{
    __shared__ u16 Kl[64 * 72];
    __shared__ u16 Vt[64 * 72];
    __shared__ u16 Pl[4 * 16 * 72];

    const int tid  = threadIdx.x;
    const int wave = tid >> 6;
    const int lane = tid & 63;
    const int l16  = lane & 15;
    const int quad = lane >> 4;

    const int bid = blockIdx.x;       // b*160 + h*16 + qt
    const int qt  = bid & 15;
    const int bh  = bid >> 4;
    const int h   = bh % HEADS;
    const int b   = bh / HEADS;
    const int q0  = qt * 64 + wave * 16;

    const size_t rowQ = (size_t)(b * S_LEN + q0 + l16) * C_DIM + h * HDIM;
    short8 qf0 = *(const short8*)(Q + rowQ + quad * 8);
    short8 qf1 = *(const short8*)(Q + rowQ + 32 + quad * 8);

    float4_ o[4] = {};
    float m_i[4], l_i[4];
    #pragma unroll
    for (int r = 0; r < 4; r++) { m_i[r] = -50.f; l_i[r] = 0.f; }

    const int srow = tid >> 3;        // 0..31 (x2 -> 64 kv rows)
    const int sdp  = tid & 7;         // 8-elem d-chunk

    for (int it = 0; it < 32; it++) {
        const int kv0 = it * 64;
        const int bs  = (kv0 < S_LEN) ? b : (b & 2);
        const int sr  = (kv0 < S_LEN) ? kv0 : (kv0 - S_LEN);
        const float shift = (kv0 < S_LEN) ? 0.f : SHIFT_C;

        __syncthreads();   // previous tile's frag reads done before restage
        #pragma unroll
        for (int i = 0; i < 2; i++) {
            int row = srow + i * 32;
            size_t g = (size_t)(bs * S_LEN + sr + row) * C_DIM + h * HDIM + sdp * 8;
            uint4 kk = *(const uint4*)(K + g);
            *(uint4*)(&Kl[row * 72 + sdp * 8]) = kk;
            union { uint4 u; u16 s[8]; } cv;
            cv.u = *(const uint4*)(V + g);
            #pragma unroll
            for (int j = 0; j < 8; j++)
                Vt[(sdp * 8 + j) * 72 + row] = cv.s[j];
        }
        __syncthreads();

        // ---- QK^T : 16x64 scores per wave ----
        float4_ sc[4];
        #pragma unroll
        for (int nc = 0; nc < 4; nc++) {
            short8 kf0 = *(const short8*)(&Kl[(nc * 16 + l16) * 72 + quad * 8]);
            short8 kf1 = *(const short8*)(&Kl[(nc * 16 + l16) * 72 + 32 + quad * 8]);
            float4_ c = {};
            c = __builtin_amdgcn_mfma_f32_16x16x32_bf16(qf0, kf0, c, 0, 0, 0);
            c = __builtin_amdgcn_mfma_f32_16x16x32_bf16(qf1, kf1, c, 0, 0, 0);
            sc[nc] = c * 0.125f + shift;
        }

        // ---- online softmax (row = quad*4+r, cols across 16 lanes) ----
        float mloc[4];
        #pragma unroll
        for (int r = 0; r < 4; r++)
            mloc[r] = fmaxf(fmaxf(sc[0][r], sc[1][r]), fmaxf(sc[2][r], sc[3][r]));
        #pragma unroll
        for (int off = 1; off < 16; off <<= 1)
            #pragma unroll
            for (int r = 0; r < 4; r++)
                mloc[r] = fmaxf(mloc[r], __shfl_xor(mloc[r], off, 64));

        float alpha[4], rs[4];
        #pragma unroll
        for (int r = 0; r < 4; r++) {
            float mnew = fmaxf(m_i[r], mloc[r]);
            alpha[r] = __expf(m_i[r] - mnew);
            m_i[r] = mnew;
            rs[r] = 0.f;
        }
        #pragma unroll
        for (int nc = 0; nc < 4; nc++)
            #pragma unroll
            for (int r = 0; r < 4; r++) {
                float p = __expf(sc[nc][r] - m_i[r]);
                rs[r] += p;
                Pl[(wave * 16 + quad * 4 + r) * 72 + nc * 16 + l16] = f2bf(p);
            }
        #pragma unroll
        for (int off = 1; off < 16; off <<= 1)
            #pragma unroll
            for (int r = 0; r < 4; r++)
                rs[r] += __shfl_xor(rs[r], off, 64);
        #pragma unroll
        for (int r = 0; r < 4; r++) l_i[r] = l_i[r] * alpha[r] + rs[r];
        #pragma unroll
        for (int dc = 0; dc < 4; dc++)
            #pragma unroll
            for (int r = 0; r < 4; r++) o[dc][r] *= alpha[r];

        __syncthreads();   // Pl writes visible before PV frag reads

        // ---- PV : O += P[16x64] x V[64x64] ----
        #pragma unroll
        for (int kc = 0; kc < 2; kc++) {
            short8 pf = *(const short8*)(&Pl[(wave * 16 + l16) * 72 + kc * 32 + quad * 8]);
            #pragma unroll
            for (int dc = 0; dc < 4; dc++) {
                short8 vf = *(const short8*)(&Vt[(dc * 16 + l16) * 72 + kc * 32 + quad * 8]);
                o[dc] = __builtin_amdgcn_mfma_f32_16x16x32_bf16(pf, vf, o[dc], 0, 0, 0);
            }
        }
    }

    float rl[4];
    #pragma unroll
    for (int r = 0; r < 4; r++) rl[r] = 1.f / l_i[r];
    #pragma unroll
    for (int dc = 0; dc < 4; dc++)
        #pragma unroll
        for (int r = 0; r < 4; r++) {
            size_t row = (size_t)(b * S_LEN + q0 + quad * 4 + r);
            Oattn[row * C_DIM + h * HDIM + dc * 16 + l16] = f2bf(o[dc][r] * rl[r]);
        }
}

// ---------------------------------------------------------------------------
extern "C" void kernel_launch(void* const* d_in, const int* in_sizes, int n_in,
                              void* d_out, int out_size, void* d_ws, size_t ws_size,
                              hipStream_t stream) {
    const void* X  = d_in[0];
    const void* Wq = d_in[1]; const void* bq = d_in[2];
    const void* Wk = d_in[3]; const void* bk = d_in[4];
    const void* Wv = d_in[5]; const void* bv = d_in[6];
    const void* Wo = d_in[7]; const void* bo = d_in[8];

    // ws layout (~19.1 MB): Xb | q | k | Wb(4) | Bf(4) | stats | flag.
    // attn aliases Xb (dead after QKV GEMM). v scratch lives in d_out (bf16;
    // d_out is >= 5.24 MB in either dtype world; dead before final GEMM).
    u16* Xb = (u16*)d_ws;
    u16* q  = Xb + TX;
    u16* k  = q + TX;
    u16* Wb = k + TX;
    float* Bf = (float*)(Wb + 4 * (size_t)WSZ);
    float* meanArr = Bf + 4 * C_DIM;
    float* stdArr  = meanArr + 2 * 4 * HEADS * HDIM;
    int* flagp = (int*)(stdArr + 2 * 4 * HEADS * HDIM);
    u16* v    = (u16*)d_out;
    u16* attn = Xb;

    const size_t TOT = TX + 4 * (size_t)WSZ + 4 * C_DIM;
    convert_inputs<<<(int)((TOT / 4 + 255) / 256), 256, 0, stream>>>(
        X, Wq, Wk, Wv, Wo, bq, bk, bv, bo, Xb, Wb, Bf, flagp);

    dim3 gQKV(M_TOT / 128, C_DIM / 128, 3);
    gemm_bt<<<gQKV, 256, 0, stream>>>(Xb, Wb, Bf, q, k, v, nullptr, flagp);

    adain_stats<<<80, 256, 0, stream>>>(q, k, meanArr, stdArr);
    adain_apply<<<(2 * 2 * S_LEN * C_DIM) / 256, 256, 0, stream>>>(q, k, meanArr, stdArr);

    attn_kernel<<<4 * HEADS * (S_LEN / 64), 256, 0, stream>>>(q, k, v, attn);

    dim3 gO(M_TOT / 128, C_DIM / 128, 1);
    gemm_bt<<<gO, 256, 0, stream>>>(attn, Wb + 3 * (size_t)WSZ, Bf + 3 * C_DIM,
                                    (u16*)d_out, (u16*)d_out, (u16*)d_out,
                                    (float*)d_out, flagp);
}

// Round 4
// 293.107 us; speedup vs baseline: 1.1438x; 1.1438x over previous
//
#include <hip/hip_runtime.h>
#include <hip/hip_bf16.h>
#include <math.h>

typedef unsigned short u16;
typedef unsigned int u32;
typedef __attribute__((ext_vector_type(8))) short short8;   // 8 bf16 = 4 VGPRs
typedef __attribute__((ext_vector_type(4))) float float4_;  // 4 fp32 acc

#define S_LEN 1024
#define C_DIM 640
#define HEADS 10
#define HDIM 64
#define M_TOT 4096                  // B*S
#define WSZ (C_DIM * C_DIM)         // 409600
#define TX ((size_t)M_TOT * C_DIM)  // 2,621,440
#define SHIFT_C 0.6931471805599453f

static __device__ __forceinline__ float bf2f(u16 u) {
    unsigned int x = ((unsigned int)u) << 16;
    float f; __builtin_memcpy(&f, &x, 4); return f;
}
static __device__ __forceinline__ u16 f2bf(float f) {
    unsigned int x; __builtin_memcpy(&x, &f, 4);
    x = x + 0x7fffu + ((x >> 16) & 1u);   // RNE
    return (u16)(x >> 16);
}

// ---------------------------------------------------------------------------
// Input-dtype probe (kept from r2): distinguishes f32 vs bf16 input worlds.
// ---------------------------------------------------------------------------
static __device__ int detect_bf16(const void* X) {
    const u32* p = (const u32*)X;
    int sane = 0;
    for (int i = 0; i < 64; i++) {
        u32 w = p[i];
        int ea = (int)((w >> 7)  & 0xFF);
        int eb = (int)((w >> 23) & 0xFF);
        sane += (ea >= 100 && ea <= 150);
        sane += (eb >= 100 && eb <= 150);
    }
    return sane >= 110;
}

// ---------------------------------------------------------------------------
// Convert inputs: X,W0..W3 -> bf16 (Xb, Wb contiguous); biases -> f32 Bf.
// ---------------------------------------------------------------------------
__global__ __launch_bounds__(256) void convert_inputs(
    const void* X, const void* W0, const void* W1, const void* W2, const void* W3,
    const void* B0, const void* B1, const void* B2, const void* B3,
    u16* __restrict__ Xb, u16* __restrict__ Wb, float* __restrict__ Bf,
    int* __restrict__ flag)
{
    __shared__ int is_bf;
    if (threadIdx.x == 0) {
        int f = detect_bf16(X);
        is_bf = f;
        if (blockIdx.x == 0) *flag = f;
    }
    __syncthreads();
    const int f = is_bf;

    const size_t WREG = TX + 4 * (size_t)WSZ;
    const size_t TOT  = WREG + 4 * C_DIM;
    size_t idx4 = ((size_t)blockIdx.x * 256 + threadIdx.x) * 4;
    if (idx4 >= TOT) return;

    const void* src; size_t off; int kind;
    u16* dst16 = nullptr; float* dstf = nullptr;
    if (idx4 < TX) {
        src = X; off = idx4; dst16 = Xb + off; kind = 0;
    } else if (idx4 < WREG) {
        size_t r = idx4 - TX; int w = (int)(r / WSZ); off = r % WSZ;
        src = (w == 0) ? W0 : ((w == 1) ? W1 : ((w == 2) ? W2 : W3));
        dst16 = Wb + (size_t)w * WSZ + off; kind = 0;
    } else {
        size_t r = idx4 - WREG; int w = (int)(r / C_DIM); off = r % C_DIM;
        src = (w == 0) ? B0 : ((w == 1) ? B1 : ((w == 2) ? B2 : B3));
        dstf = Bf + (size_t)w * C_DIM + off; kind = 1;
    }

    if (!f) {
        float4 v = *(const float4*)((const float*)src + off);
        if (kind == 0) {
            union { u16 s[4]; uint2 u; } pk;
            pk.s[0] = f2bf(v.x); pk.s[1] = f2bf(v.y);
            pk.s[2] = f2bf(v.z); pk.s[3] = f2bf(v.w);
            *(uint2*)dst16 = pk.u;
        } else {
            *(float4*)dstf = v;
        }
    } else {
        union { uint2 u; u16 s[4]; } pk;
        pk.u = *(const uint2*)((const u16*)src + off);
        if (kind == 0) {
            *(uint2*)dst16 = pk.u;
        } else {
            dstf[0] = bf2f(pk.s[0]); dstf[1] = bf2f(pk.s[1]);
            dstf[2] = bf2f(pk.s[2]); dstf[3] = bf2f(pk.s[3]);
        }
    }
}

// ---------------------------------------------------------------------------
// GEMM: Out = A @ W^T + bias. 128x128 tile, BK=32, double-buffered LDS +
// register prefetch, ONE barrier per K-iter (global-load latency overlapped
// with MFMA of the previous tile). LDS ld 40 (2-way conflicts only, free).
// ---------------------------------------------------------------------------
__global__ __launch_bounds__(256) void gemm_bt(
    const u16* __restrict__ A, const u16* __restrict__ Wbase,
    const float* __restrict__ Bf,
    u16* O0, u16* O1, u16* O2,
    float* Of, const int* __restrict__ flag)
{
    const int z = blockIdx.z;
    const u16* W    = Wbase + (size_t)z * WSZ;
    const float* bias = Bf + (size_t)z * C_DIM;
    u16* Out = (z == 0) ? O0 : ((z == 1) ? O1 : O2);
    const bool wf32 = (Of != nullptr) && (*flag == 0);

    __shared__ u16 Al[2][128 * 40];
    __shared__ u16 Wl[2][128 * 40];

    const int tid  = threadIdx.x;
    const int wave = tid >> 6;
    const int lane = tid & 63;
    const int l16  = lane & 15;
    const int quad = lane >> 4;
    const int m0 = blockIdx.x * 128;
    const int n0 = blockIdx.y * 128;
    const int wm = (wave & 1) * 64;
    const int wn = (wave >> 1) * 64;

    const int srow = tid >> 2;          // 0..63 (two passes -> 128 rows)
    const int scol = (tid & 3) * 8;     // k-offset in elements

    float4_ acc[4][4] = {};
    uint4 va[2], vw[2];

    // prologue: tile 0 -> regs -> LDS buf 0
    #pragma unroll
    for (int i = 0; i < 2; i++) {
        int row = srow + i * 64;
        va[i] = *(const uint4*)(A + (size_t)(m0 + row) * C_DIM + scol);
        vw[i] = *(const uint4*)(W + (size_t)(n0 + row) * C_DIM + scol);
    }
    #pragma unroll
    for (int i = 0; i < 2; i++) {
        int row = srow + i * 64;
        *(uint4*)(&Al[0][row * 40 + scol]) = va[i];
        *(uint4*)(&Wl[0][row * 40 + scol]) = vw[i];
    }

    const int NIT = C_DIM / 32;   // 20
    for (int kt = 0; kt < NIT; kt++) {
        const int buf = kt & 1;
        __syncthreads();

        if (kt + 1 < NIT) {
            int k0 = (kt + 1) * 32;
            #pragma unroll
            for (int i = 0; i < 2; i++) {
                int row = srow + i * 64;
                va[i] = *(const uint4*)(A + (size_t)(m0 + row) * C_DIM + k0 + scol);
                vw[i] = *(const uint4*)(W + (size_t)(n0 + row) * C_DIM + k0 + scol);
            }
        }

        short8 af[4], bfr[4];
        #pragma unroll
        for (int t = 0; t < 4; t++) {
            af[t]  = *(const short8*)(&Al[buf][(wm + t * 16 + l16) * 40 + quad * 8]);
            bfr[t] = *(const short8*)(&Wl[buf][(wn + t * 16 + l16) * 40 + quad * 8]);
        }
        #pragma unroll
        for (int mt = 0; mt < 4; mt++)
            #pragma unroll
            for (int nt = 0; nt < 4; nt++)
                acc[mt][nt] = __builtin_amdgcn_mfma_f32_16x16x32_bf16(
                    af[mt], bfr[nt], acc[mt][nt], 0, 0, 0);

        if (kt + 1 < NIT) {
            #pragma unroll
            for (int i = 0; i < 2; i++) {
                int row = srow + i * 64;
                *(uint4*)(&Al[buf ^ 1][row * 40 + scol]) = va[i];
                *(uint4*)(&Wl[buf ^ 1][row * 40 + scol]) = vw[i];
            }
        }
    }

    #pragma unroll
    for (int mt = 0; mt < 4; mt++) {
        #pragma unroll
        for (int nt = 0; nt < 4; nt++) {
            int col = n0 + wn + nt * 16 + l16;
            float bv = bias[col];
            #pragma unroll
            for (int r = 0; r < 4; r++) {
                int row = m0 + wm + mt * 16 + quad * 4 + r;
                float val = acc[mt][nt][r] + bv;
                size_t idx = (size_t)row * C_DIM + col;
                if (wf32) Of[idx] = val;
                else      Out[idx] = f2bf(val);
            }
        }
    }
}

// ---------------------------------------------------------------------------
// AdaIN stats: per (tensor t in {q,k}, b, h, d): mean/std over S (ddof=1).
// ---------------------------------------------------------------------------
__global__ __launch_bounds__(256) void adain_stats(
    const u16* __restrict__ Qp, const u16* __restrict__ Kp,
    float* __restrict__ meanArr, float* __restrict__ stdArr)
{
    const int bid = blockIdx.x;          // t*40 + b*10 + h
    const int t = bid / 40;
    const int rem = bid % 40;
    const int b = rem / 10;
    const int h = rem % 10;
    const u16* X = t ? Kp : Qp;

    const int tid = threadIdx.x;
    const int d  = tid & 63;
    const int sg = tid >> 6;

    float sum = 0.f, sq = 0.f;
    for (int s = sg; s < S_LEN; s += 4) {
        float v = bf2f(X[(size_t)(b * S_LEN + s) * C_DIM + h * HDIM + d]);
        sum += v; sq += v * v;
    }
    __shared__ float ssum[4][64], ssq[4][64];
    ssum[sg][d] = sum; ssq[sg][d] = sq;
    __syncthreads();
    if (tid < 64) {
        float Sv = 0.f, Qv = 0.f;
        #pragma unroll
        for (int g = 0; g < 4; g++) { Sv += ssum[g][tid]; Qv += ssq[g][tid]; }
        float mean = Sv * (1.f / 1024.f);
        float var  = (Qv - Sv * Sv * (1.f / 1024.f)) * (1.f / 1023.f);
        int idx = ((t * 4 + b) * HEADS + h) * HDIM + tid;
        meanArr[idx] = mean;
        stdArr[idx]  = sqrtf(fmaxf(var, 0.f) + 1e-5f);
    }
}

// ---------------------------------------------------------------------------
// AdaIN apply: restyle batches 1 and 3 in-place (ref = batch-1). 0,2 identity.
// ---------------------------------------------------------------------------
__global__ __launch_bounds__(256) void adain_apply(
    u16* __restrict__ Qp, u16* __restrict__ Kp,
    const float* __restrict__ meanArr, const float* __restrict__ stdArr)
{
    const int idx = blockIdx.x * 256 + threadIdx.x;   // 2*2*1024*640 exact
    const int t  = idx / (2 * S_LEN * C_DIM);
    const int r  = idx % (2 * S_LEN * C_DIM);
    const int bi = r / (S_LEN * C_DIM);               // 0,1 -> b=1,3
    const int r2 = r % (S_LEN * C_DIM);
    const int s  = r2 / C_DIM;
    const int c  = r2 % C_DIM;
    const int b  = bi * 2 + 1;
    const int h  = c / HDIM, d = c % HDIM;

    u16* X = t ? Kp : Qp;
    const int si   = ((t * 4 + b) * HEADS + h) * HDIM + d;
    const int sref = ((t * 4 + (b - 1)) * HEADS + h) * HDIM + d;
    float scale = stdArr[sref] / stdArr[si];
    float off   = meanArr[sref] - meanArr[si] * scale;
    size_t g = (size_t)(b * S_LEN + s) * C_DIM + c;
    X[g] = f2bf(bf2f(X[g]) * scale + off);
}

// ---------------------------------------------------------------------------
// Flash attention, round-4 structure:
//  - double-buffered K/V LDS, register prefetch of tile t+1 during tile t,
//    ONE __syncthreads per kv-tile (32 total).
//  - V staged TRANSPOSED via coalesced scalar-u16 gathers (lane = d, 2B/lane
//    contiguous per j) packed to short8 -> single b128 LDS write per chunk.
//    Kills the r3 16-way ds_write_b16 conflicts (2.4e7 SQ_LDS_BANK_CONFLICT).
//  - P round-trip through LDS is wave-local; fenced with lgkmcnt(0) (DS ops
//    are wave-ordered), no block barrier.
// ---------------------------------------------------------------------------
__global__ __launch_bounds__(256) void attn_kernel(
    const u16* __restrict__ Q, const u16* __restrict__ K, const u16* __restrict__ V,
    u16* __restrict__ Oattn)
{
    __shared__ u16 Kl[2][64 * 72];
    __shared__ u16 Vt[2][64 * 72];
    __shared__ u16 Pl[4 * 16 * 72];

    const int tid  = threadIdx.x;
    const int wave = tid >> 6;
    const int lane = tid & 63;
    const int l16  = lane & 15;
    const int quad = lane >> 4;

    const int bid = blockIdx.x;       // b*160 + h*16 + qt
    const int qt  = bid & 15;
    const int bh  = bid >> 4;
    const int h   = bh % HEADS;
    const int b   = bh / HEADS;
    const int q0  = qt * 64 + wave * 16;

    const size_t rowQ = (size_t)(b * S_LEN + q0 + l16) * C_DIM + h * HDIM;
    short8 qf0 = *(const short8*)(Q + rowQ + quad * 8);
    short8 qf1 = *(const short8*)(Q + rowQ + 32 + quad * 8);

    float4_ o[4] = {};
    float m_i[4], l_i[4];
    #pragma unroll
    for (int r = 0; r < 4; r++) { m_i[r] = -50.f; l_i[r] = 0.f; }

    // K staging: thread = (srow = tid>>3 in 0..31 [x2], sdp = tid&7)
    const int srow = tid >> 3;
    const int sdp  = tid & 7;
    // V staging: thread = (d = tid&63, chunk c = tid>>6 [+4])
    const int vd = tid & 63;
    const int vc0 = tid >> 6;

    uint4 kreg[2];
    union { short8 v; u16 s[8]; } vreg[2];

    // ---- prologue: load tile 0 -> regs -> LDS buf 0 ----
    {
        const int bs = b, sr = 0;
        #pragma unroll
        for (int i = 0; i < 2; i++) {
            int row = srow + i * 32;
            kreg[i] = *(const uint4*)(K + (size_t)(bs * S_LEN + sr + row) * C_DIM + h * HDIM + sdp * 8);
        }
        #pragma unroll
        for (int ci = 0; ci < 2; ci++) {
            int c = vc0 + ci * 4;
            #pragma unroll
            for (int j = 0; j < 8; j++)
                vreg[ci].s[j] = V[(size_t)(bs * S_LEN + sr + c * 8 + j) * C_DIM + h * HDIM + vd];
        }
        #pragma unroll
        for (int i = 0; i < 2; i++) {
            int row = srow + i * 32;
            *(uint4*)(&Kl[0][row * 72 + sdp * 8]) = kreg[i];
        }
        #pragma unroll
        for (int ci = 0; ci < 2; ci++) {
            int c = vc0 + ci * 4;
            *(short8*)(&Vt[0][vd * 72 + c * 8]) = vreg[ci].v;
        }
    }

    for (int it = 0; it < 32; it++) {
        const int buf = it & 1;
        const float shift = (it < 16) ? 0.f : SHIFT_C;

        __syncthreads();   // buf's writes visible; prior reads of buf^1 done

        // ---- prefetch tile it+1 into regs (global, non-blocking) ----
        if (it + 1 < 32) {
            const int kv0n = (it + 1) * 64;
            const int bsn  = (kv0n < S_LEN) ? b : (b & 2);
            const int srn  = (kv0n < S_LEN) ? kv0n : (kv0n - S_LEN);
            #pragma unroll
            for (int i = 0; i < 2; i++) {
                int row = srow + i * 32;
                kreg[i] = *(const uint4*)(K + (size_t)(bsn * S_LEN + srn + row) * C_DIM + h * HDIM + sdp * 8);
            }
            #pragma unroll
            for (int ci = 0; ci < 2; ci++) {
                int c = vc0 + ci * 4;
                #pragma unroll
                for (int j = 0; j < 8; j++)
                    vreg[ci].s[j] = V[(size_t)(bsn * S_LEN + srn + c * 8 + j) * C_DIM + h * HDIM + vd];
            }
        }

        // ---- QK^T : 16x64 scores per wave ----
        float4_ sc[4];
        #pragma unroll
        for (int nc = 0; nc < 4; nc++) {
            short8 kf0 = *(const short8*)(&Kl[buf][(nc * 16 + l16) * 72 + quad * 8]);
            short8 kf1 = *(const short8*)(&Kl[buf][(nc * 16 + l16) * 72 + 32 + quad * 8]);
            float4_ c = {};
            c = __builtin_amdgcn_mfma_f32_16x16x32_bf16(qf0, kf0, c, 0, 0, 0);
            c = __builtin_amdgcn_mfma_f32_16x16x32_bf16(qf1, kf1, c, 0, 0, 0);
            sc[nc] = c * 0.125f + shift;
        }

        // ---- online softmax (row = quad*4+r, cols across 16 lanes) ----
        float mloc[4];
        #pragma unroll
        for (int r = 0; r < 4; r++)
            mloc[r] = fmaxf(fmaxf(sc[0][r], sc[1][r]), fmaxf(sc[2][r], sc[3][r]));
        #pragma unroll
        for (int off = 1; off < 16; off <<= 1)
            #pragma unroll
            for (int r = 0; r < 4; r++)
                mloc[r] = fmaxf(mloc[r], __shfl_xor(mloc[r], off, 64));

        float alpha[4], rs[4];
        #pragma unroll
        for (int r = 0; r < 4; r++) {
            float mnew = fmaxf(m_i[r], mloc[r]);
            alpha[r] = __expf(m_i[r] - mnew);
            m_i[r] = mnew;
            rs[r] = 0.f;
        }
        #pragma unroll
        for (int nc = 0; nc < 4; nc++)
            #pragma unroll
            for (int r = 0; r < 4; r++) {
                float p = __expf(sc[nc][r] - m_i[r]);
                rs[r] += p;
                Pl[(wave * 16 + quad * 4 + r) * 72 + nc * 16 + l16] = f2bf(p);
            }
        #pragma unroll
        for (int off = 1; off < 16; off <<= 1)
            #pragma unroll
            for (int r = 0; r < 4; r++)
                rs[r] += __shfl_xor(rs[r], off, 64);
        #pragma unroll
        for (int r = 0; r < 4; r++) l_i[r] = l_i[r] * alpha[r] + rs[r];
        #pragma unroll
        for (int dc = 0; dc < 4; dc++)
            #pragma unroll
            for (int r = 0; r < 4; r++) o[dc][r] *= alpha[r];

        // wave-local LDS RAW fence for Pl (DS ops are wave-ordered)
        asm volatile("s_waitcnt lgkmcnt(0)" ::: "memory");

        // ---- PV : O += P[16x64] x V[64x64] ----
        #pragma unroll
        for (int kc = 0; kc < 2; kc++) {
            short8 pf = *(const short8*)(&Pl[(wave * 16 + l16) * 72 + kc * 32 + quad * 8]);
            #pragma unroll
            for (int dc = 0; dc < 4; dc++) {
                short8 vf = *(const short8*)(&Vt[buf][(dc * 16 + l16) * 72 + kc * 32 + quad * 8]);
                o[dc] = __builtin_amdgcn_mfma_f32_16x16x32_bf16(pf, vf, o[dc], 0, 0, 0);
            }
        }

        // ---- stage prefetched regs into the other buffer ----
        if (it + 1 < 32) {
            #pragma unroll
            for (int i = 0; i < 2; i++) {
                int row = srow + i * 32;
                *(uint4*)(&Kl[buf ^ 1][row * 72 + sdp * 8]) = kreg[i];
            }
            #pragma unroll
            for (int ci = 0; ci < 2; ci++) {
                int c = vc0 + ci * 4;
                *(short8*)(&Vt[buf ^ 1][vd * 72 + c * 8]) = vreg[ci].v;
            }
        }
    }

    float rl[4];
    #pragma unroll
    for (int r = 0; r < 4; r++) rl[r] = 1.f / l_i[r];
    #pragma unroll
    for (int dc = 0; dc < 4; dc++)
        #pragma unroll
        for (int r = 0; r < 4; r++) {
            size_t row = (size_t)(b * S_LEN + q0 + quad * 4 + r);
            Oattn[row * C_DIM + h * HDIM + dc * 16 + l16] = f2bf(o[dc][r] * rl[r]);
        }
}

// ---------------------------------------------------------------------------
extern "C" void kernel_launch(void* const* d_in, const int* in_sizes, int n_in,
                              void* d_out, int out_size, void* d_ws, size_t ws_size,
                              hipStream_t stream) {
    const void* X  = d_in[0];
    const void* Wq = d_in[1]; const void* bq = d_in[2];
    const void* Wk = d_in[3]; const void* bk = d_in[4];
    const void* Wv = d_in[5]; const void* bv = d_in[6];
    const void* Wo = d_in[7]; const void* bo = d_in[8];

    // ws layout (~19.1 MB): Xb | q | k | Wb(4) | Bf(4) | stats | flag.
    // attn aliases Xb (dead after QKV GEMM). v scratch lives in d_out (dead
    // before final GEMM overwrites it).
    u16* Xb = (u16*)d_ws;
    u16* q  = Xb + TX;
    u16* k  = q + TX;
    u16* Wb = k + TX;
    float* Bf = (float*)(Wb + 4 * (size_t)WSZ);
    float* meanArr = Bf + 4 * C_DIM;
    float* stdArr  = meanArr + 2 * 4 * HEADS * HDIM;
    int* flagp = (int*)(stdArr + 2 * 4 * HEADS * HDIM);
    u16* v    = (u16*)d_out;
    u16* attn = Xb;

    const size_t TOT = TX + 4 * (size_t)WSZ + 4 * C_DIM;
    convert_inputs<<<(int)((TOT / 4 + 255) / 256), 256, 0, stream>>>(
        X, Wq, Wk, Wv, Wo, bq, bk, bv, bo, Xb, Wb, Bf, flagp);

    dim3 gQKV(M_TOT / 128, C_DIM / 128, 3);
    gemm_bt<<<gQKV, 256, 0, stream>>>(Xb, Wb, Bf, q, k, v, nullptr, flagp);

    adain_stats<<<80, 256, 0, stream>>>(q, k, meanArr, stdArr);
    adain_apply<<<(2 * 2 * S_LEN * C_DIM) / 256, 256, 0, stream>>>(q, k, meanArr, stdArr);

    attn_kernel<<<4 * HEADS * (S_LEN / 64), 256, 0, stream>>>(q, k, v, attn);

    dim3 gO(M_TOT / 128, C_DIM / 128, 1);
    gemm_bt<<<gO, 256, 0, stream>>>(attn, Wb + 3 * (size_t)WSZ, Bf + 3 * C_DIM,
                                    (u16*)d_out, (u16*)d_out, (u16*)d_out,
                                    (float*)d_out, flagp);
}